// Round 6
// baseline (1297.750 us; speedup 1.0000x reference)
//
#include <hip/hip_runtime.h>
#include <math.h>

#define N_PTS  131072
#define DIM    128
#define NBOOK  4
#define KCODES 1024

#define CHUNK   32                   // codes per LDS chunk
#define PT      2                    // point tiles (32 pts each) per wave -> 64 pts/wave
#define BPTS    256                  // 4 waves * 64 points
#define CHUNK_BYTES 8320             // 4096 c_hi + 4096 c_lo + 128 cq(f32[32])
#define EPS_ACC 0.016f               // ~7.4 sigma of rounding error + pack-mask slop
#define WLB_CAP 32768                // per-book worklist cap (4 books = 512 KB total)

// two-level int8 fixed point: v ~= h/18 + l/4096  (residual <= 1/8192)
#define S1     18.0f
#define INV_S1 (1.0f/18.0f)
#define S2     4096.0f
#define INV1   (1.0f/324.0f)         // hh:  1/(18*18)
#define INV2   (1.0f/73728.0f)       // mid: 1/(18*4096)
#define INV3   (1.0f/16777216.0f)    // ll:  1/(4096*4096) = 2^-24

typedef int   i32x4  __attribute__((ext_vector_type(4)));
typedef int   i32x16 __attribute__((ext_vector_type(16)));
typedef float f32x4  __attribute__((ext_vector_type(4)));
typedef float f32x16 __attribute__((ext_vector_type(16)));

// ws layout: cbf (4*32*8320 = 1064960 B) | csq fp32[4096] | counters int[4] | worklist int[4][32768]
#define WS_CSQ_OFF  2359296u
#define WS_CNT_OFF  (WS_CSQ_OFF + 16384u)
#define WS_WL_OFF   (WS_CNT_OFF + 256u)

__device__ inline void quant2(float v, int& h, int& l) {
    float hf = rintf(v * S1);
    hf = fminf(fmaxf(hf, -127.f), 127.f);
    float r  = v - hf * INV_S1;
    float lf = rintf(r * S2);                      // |r|<=1/36 -> |lf|<=114, no clamp
    lf = fminf(fmaxf(lf, -127.f), 127.f);
    h = (int)hf; l = (int)lf;
}

__device__ inline void async_copy16(const void* g, void* l) {
    __builtin_amdgcn_global_load_lds(
        (const __attribute__((address_space(1))) void*)g,
        (__attribute__((address_space(3))) void*)l,
        16, 0, 0);
}

// ---------------- prep: codebook -> int8 A-fragments (32x32x32) + cq + csq -------------
// cbf per (b,chunk): [0,4096) c_hi frags, [4096,8192) c_lo frags, [8192,8320) cq f32[32]
// frag: s (0..3) * 1024 + lane*16; byte j: code = chunk*32 + (lane&31),
//       k = s*32 + (lane>>5)*16 + j  (same k-map used for B side -> permutation-safe)
// cq[code] = 320 - csq[code]/2  (f32)
__global__ __launch_bounds__(256)
void prep_kernel(const float* __restrict__ cb, char* __restrict__ cbf,
                 float* __restrict__ csq, int* __restrict__ counters) {
    if (blockIdx.x >= 256) {                       // csq + cq + counter blocks (16)
        int idx = (blockIdx.x - 256) * 256 + threadIdx.x;   // 0..4095
        if (idx < 4) counters[idx] = 0;
        const float4* p = (const float4*)(cb + (size_t)idx * DIM);
        float s = 0.f;
#pragma unroll
        for (int i = 0; i < DIM / 4; ++i) {
            float4 v = p[i];
            s += v.x * v.x + v.y * v.y + v.z * v.z + v.w * v.w;
        }
        csq[idx] = s;
        int b = idx >> 10, k = idx & 1023;
        *(float*)(cbf + (size_t)(b * 32 + (k >> 5)) * CHUNK_BYTES + 8192 + (k & 31) * 4)
            = 320.0f - 0.5f * s;
        return;
    }
    int t     = blockIdx.x * 256 + threadIdx.x;    // 0..65535
    int lane  = t & 63;
    int s     = (t >> 6) & 3;
    int plane = (t >> 8) & 1;
    int bc    = t >> 9;                            // 0..127  (b*32 + chunk)
    int code  = (bc & 31) * CHUNK + (lane & 31);
    int b     = bc >> 5;
    int kb    = s * 32 + (lane >> 5) * 16;

    const float* row = cb + ((size_t)b * KCODES + code) * DIM + kb;
    float4 v0 = ((const float4*)row)[0];
    float4 v1 = ((const float4*)row)[1];
    float4 v2 = ((const float4*)row)[2];
    float4 v3 = ((const float4*)row)[3];
    float vals[16] = {v0.x, v0.y, v0.z, v0.w, v1.x, v1.y, v1.z, v1.w,
                      v2.x, v2.y, v2.z, v2.w, v3.x, v3.y, v3.z, v3.w};
    unsigned o[4] = {0, 0, 0, 0};
#pragma unroll
    for (int j = 0; j < 16; ++j) {
        int h, l;
        quant2(vals[j], h, l);
        int q = plane ? l : h;
        o[j >> 2] |= ((unsigned)(q & 255)) << ((j & 3) * 8);
    }
    *(uint4*)(cbf + (size_t)bc * CHUNK_BYTES + plane * 4096 + s * 1024 + lane * 16)
        = make_uint4(o[0], o[1], o[2], o[3]);
}

// ---------------- main: dbuf LDS, 32 int8 MFMAs/chunk (full 16-bit), deferred top-2 ----
// grid (512, 2): block y handles books {2y, 2y+1} as one 64-chunk stream.
// Per chunk: MFMAs (hh, mid, ll products) -> in-phase fold to f32 pv -> top-2 packing
// DEFERRED one chunk (overlaps next chunk's MFMA stream). Int accs reused each chunk;
// pv single-buffered (consumed by top2 before fold rewrites) -> ~200 VGPR, no spill.
__global__ __launch_bounds__(256, 2)
void argmin_mfma_kernel(const float* __restrict__ x,
                        const char* __restrict__ cbf,
                        int* __restrict__ out,
                        int* __restrict__ counters,
                        int* __restrict__ worklist) {
    __shared__ i32x4 ldsv[2 * CHUNK_BYTES / 16];   // 16640 B (two 8.3 KB buffers)

    const int tid  = threadIdx.x;
    const int lane = tid & 63;
    const int w    = tid >> 6;
    const int n0   = blockIdx.x * BPTS;
    const int col  = lane & 31;
    const int kh   = lane >> 5;

    const char* src0 = cbf + (size_t)(blockIdx.y * 64) * CHUNK_BYTES;
    char* ldsb = (char*)ldsv;

    auto issue = [&](int c) {                      // stage chunk c -> buf[c&1]
        const char* src = src0 + (size_t)c * CHUNK_BYTES;
        char* dst = ldsb + (c & 1) * CHUNK_BYTES;
#pragma unroll
        for (int i = 0; i < 2; ++i)
            async_copy16(src + i * 4096 + tid * 16, dst + i * 4096 + w * 1024);
        if (w == 0 && lane < 8)
            async_copy16(src + 8192 + lane * 16, dst + 8192);
    };

    issue(0);                                      // chunk 0 in flight during x-quant

    // ---- B fragments (points), int8 hi+lo, in regs (overlaps chunk-0 staging) ----
    i32x4 xh[PT][4], xl[PT][4];
#pragma unroll
    for (int pt = 0; pt < PT; ++pt) {
        const float* xrow = x + (size_t)(n0 + w * 64 + pt * 32 + col) * DIM;
#pragma unroll
        for (int s = 0; s < 4; ++s) {
            const float* p = xrow + s * 32 + kh * 16;
            float4 v0 = ((const float4*)p)[0];
            float4 v1 = ((const float4*)p)[1];
            float4 v2 = ((const float4*)p)[2];
            float4 v3 = ((const float4*)p)[3];
            float vals[16] = {v0.x, v0.y, v0.z, v0.w, v1.x, v1.y, v1.z, v1.w,
                              v2.x, v2.y, v2.z, v2.w, v3.x, v3.y, v3.z, v3.w};
            unsigned oh[4] = {0, 0, 0, 0}, ol[4] = {0, 0, 0, 0};
#pragma unroll
            for (int j = 0; j < 16; ++j) {
                int h, l;
                quant2(vals[j], h, l);
                oh[j >> 2] |= ((unsigned)(h & 255)) << ((j & 3) * 8);
                ol[j >> 2] |= ((unsigned)(l & 255)) << ((j & 3) * 8);
            }
            i32x4 hv = {(int)oh[0], (int)oh[1], (int)oh[2], (int)oh[3]};
            i32x4 lv = {(int)ol[0], (int)ol[1], (int)ol[2], (int)ol[3]};
            xh[pt][s] = hv;
            xl[pt][s] = lv;
        }
    }

    unsigned b1p[PT], b2p[PT];
    int bchunk[PT];
#pragma unroll
    for (int pt = 0; pt < PT; ++pt) { b1p[pt] = 0u; b2p[pt] = 0u; bchunk[pt] = 0; }

    i32x16 hh[PT], mm[PT], llq[PT];
    f32x16 pv[PT];

    auto top2 = [&](int cc) {                      // packed top-2 on pv, larger = nearer
        int ci = cc & 31;
#pragma unroll
        for (int pt = 0; pt < PT; ++pt) {
            unsigned prev = b1p[pt], p1v = prev, p2v = b2p[pt];
#pragma unroll
            for (int r = 0; r < 16; r += 2) {
                unsigned pa = (__float_as_uint(pv[pt][r])     & 0xFFFFFFE0u) | (31u - (unsigned)r);
                unsigned pb = (__float_as_uint(pv[pt][r + 1]) & 0xFFFFFFE0u) | (30u - (unsigned)r);
                unsigned hi = pa > pb ? pa : pb;
                unsigned lo = pa < pb ? pa : pb;
                unsigned t2 = hi < p1v ? hi : p1v;
                unsigned m  = lo > t2 ? lo : t2;
                p2v = p2v > m ? p2v : m;           // -> v_max3
                p1v = p1v > hi ? p1v : hi;
            }
            bchunk[pt] = (p1v != prev) ? ci : bchunk[pt];
            b1p[pt] = p1v; b2p[pt] = p2v;
        }
    };

    auto finalize = [&](int book) {
        int b = blockIdx.y * 2 + book;
#pragma unroll
        for (int pt = 0; pt < PT; ++pt) {
            unsigned r = 31u - (b1p[pt] & 31u);    // leaf 0..15
            float m1 = __uint_as_float(b1p[pt] & 0xFFFFFFE0u);
            float m2 = __uint_as_float(b2p[pt] & 0xFFFFFFE0u);
            int row = (int)((r & 3u) + 8u * (r >> 2)) + 4 * kh;
            int code = bchunk[pt] * CHUNK + row;
            float om1 = __shfl_xor(m1, 32);
            float om2 = __shfl_xor(m2, 32);
            int   oc  = __shfl_xor(code, 32);
            bool take = (om1 > m1) || (om1 == m1 && oc < code);
            float nm2 = fmaxf(fminf(m1, om1), fmaxf(m2, om2));
            if (take) { m1 = om1; code = oc; }
            m2 = nm2;
            if (lane < 32) {
                int point = n0 + w * 64 + pt * 32 + col;
                out[point * NBOOK + b] = code;
                if (m1 - m2 < EPS_ACC) {
                    int pos = atomicAdd(&counters[b], 1);
                    if (pos < WLB_CAP) worklist[b * WLB_CAP + pos] = point;
                }
            }
            b1p[pt] = 0u; b2p[pt] = 0u; bchunk[pt] = 0;
        }
    };

    __syncthreads();                               // chunk 0 visible

    for (int c = 0; c < 64; ++c) {
        if (c + 1 < 64) issue(c + 1);              // stage next into other buffer
        const char* A = ldsb + (c & 1) * CHUNK_BYTES;

        // ---- 32 MFMAs: hh, mid (hl+lh), ll ----
#pragma unroll
        for (int pt = 0; pt < PT; ++pt)
#pragma unroll
            for (int r = 0; r < 16; ++r) { hh[pt][r] = 0; mm[pt][r] = 0; llq[pt][r] = 0; }
#pragma unroll
        for (int s = 0; s < 4; ++s) {
            i32x4 chi = *(const i32x4*)(A + s * 1024 + lane * 16);
            i32x4 clo = *(const i32x4*)(A + 4096 + s * 1024 + lane * 16);
#pragma unroll
            for (int pt = 0; pt < PT; ++pt) {
                hh[pt]  = __builtin_amdgcn_mfma_i32_32x32x32_i8(chi, xh[pt][s], hh[pt], 0, 0, 0);
                mm[pt]  = __builtin_amdgcn_mfma_i32_32x32x32_i8(clo, xh[pt][s], mm[pt], 0, 0, 0);
                mm[pt]  = __builtin_amdgcn_mfma_i32_32x32x32_i8(chi, xl[pt][s], mm[pt], 0, 0, 0);
                llq[pt] = __builtin_amdgcn_mfma_i32_32x32x32_i8(clo, xl[pt][s], llq[pt], 0, 0, 0);
            }
        }

        // ---- deferred top-2 of previous chunk (VALU, overlaps MFMA pipe) ----
        if (c > 0) {
            top2(c - 1);
            if (c == 32) finalize(0);              // after chunk-31 top2
        }

        // ---- fold this chunk's int accs to f32 pv (in-phase, cheap) ----
        f32x4 cqv[4];
#pragma unroll
        for (int g = 0; g < 4; ++g)
            cqv[g] = *(const f32x4*)(A + 8192 + kh * 16 + g * 32);
#pragma unroll
        for (int pt = 0; pt < PT; ++pt)
#pragma unroll
            for (int r = 0; r < 16; ++r)
                pv[pt][r] = fmaf((float)hh[pt][r], INV1,
                            fmaf((float)mm[pt][r], INV2,
                            fmaf((float)llq[pt][r], INV3, cqv[r >> 2][r & 3])));

        __syncthreads();                           // staging done; LDS reads done
    }
    top2(63);
    finalize(1);
}

// ---------------- fallback: exact fp32, batched (64 items/block, broadcast codebook) ---
// grid (256, 4): y = book. Wave w scans codes [w*256, w*256+256) for its 64 items;
// all 64 lanes read the SAME codebook row (L1/L2 broadcast) -> 8 KB/item vs 512 KB.
__global__ __launch_bounds__(256)
void exact_kernel(const float* __restrict__ x,
                  const float* __restrict__ cb,
                  const float* __restrict__ csq,
                  const int* __restrict__ counters,
                  const int* __restrict__ worklist,
                  int* __restrict__ out) {
    __shared__ float xs[64][132];                  // pad 132: 16B-aligned rows
    __shared__ float rbd[256];
    __shared__ int   rbi[256];

    const int b = blockIdx.y;
    int n = counters[b];
    if (n > WLB_CAP) n = WLB_CAP;
    const int t = threadIdx.x, j = t & 63, w = t >> 6;

    for (int bt = blockIdx.x; bt * 64 < n; bt += gridDim.x) {
        __syncthreads();                           // xs safe to overwrite
        int ii = bt * 64 + j;
        int pidx = worklist[b * WLB_CAP + (ii < n ? ii : 0)];
        const float* xr = x + (size_t)pidx * DIM + w * 32;
#pragma unroll
        for (int i = 0; i < 8; ++i)
            *(float4*)&xs[j][w * 32 + i * 4] = ((const float4*)xr)[i];
        __syncthreads();

        const float* cbb = cb + ((size_t)b * KCODES + w * 256) * DIM;
        const float* cs  = csq + b * KCODES + w * 256;
        float bd = 3.4e38f;
        int   bi = 0;
        for (int cc = 0; cc < 64; ++cc) {
            const float* crow[4];
#pragma unroll
            for (int q = 0; q < 4; ++q)
                crow[q] = cbb + (size_t)(q * 64 + cc) * DIM;
            float dots[4] = {0.f, 0.f, 0.f, 0.f};
#pragma unroll 4
            for (int d = 0; d < DIM; d += 4) {
                float4 xv = *(const float4*)&xs[j][d];
#pragma unroll
                for (int q = 0; q < 4; ++q) {
                    float4 cv = *(const float4*)(crow[q] + d);
                    dots[q] += xv.x * cv.x + xv.y * cv.y + xv.z * cv.z + xv.w * cv.w;
                }
            }
#pragma unroll
            for (int q = 0; q < 4; ++q) {
                int k = w * 256 + q * 64 + cc;
                float dist = cs[q * 64 + cc] - 2.f * dots[q];
                if (dist < bd || (dist == bd && k < bi)) { bd = dist; bi = k; }
            }
        }
        rbd[t] = bd; rbi[t] = bi;
        __syncthreads();
        if (t < 64 && bt * 64 + t < n) {
            float fb = rbd[t]; int fi = rbi[t];
#pragma unroll
            for (int q = 1; q < 4; ++q) {
                float od = rbd[t + q * 64]; int oi = rbi[t + q * 64];
                if (od < fb || (od == fb && oi < fi)) { fb = od; fi = oi; }
            }
            int point = worklist[b * WLB_CAP + bt * 64 + t];
            out[point * NBOOK + b] = fi;
        }
    }
}

extern "C" void kernel_launch(void* const* d_in, const int* in_sizes, int n_in,
                              void* d_out, int out_size, void* d_ws, size_t ws_size,
                              hipStream_t stream) {
    const float* x  = (const float*)d_in[0];   // [N, D] fp32
    const float* cb = (const float*)d_in[1];   // [B, K, D] fp32
    int* out = (int*)d_out;                    // [N, B] int32

    char* ws = (char*)d_ws;
    char*  cbf      = ws;
    float* csq      = (float*)(ws + WS_CSQ_OFF);
    int*   counters = (int*)(ws + WS_CNT_OFF);
    int*   worklist = (int*)(ws + WS_WL_OFF);

    prep_kernel<<<272, 256, 0, stream>>>(cb, cbf, csq, counters);

    argmin_mfma_kernel<<<dim3(N_PTS / BPTS, 2), 256, 0, stream>>>(x, cbf, out, counters, worklist);

    exact_kernel<<<dim3(256, 4), 256, 0, stream>>>(x, cb, csq, counters, worklist, out);
}

// Round 7
// 371.132 us; speedup vs baseline: 3.4967x; 3.4967x over previous
//
#include <hip/hip_runtime.h>
#include <math.h>

#define N_PTS  131072
#define DIM    128
#define NBOOK  4
#define KCODES 1024

#define CHUNK   32                   // codes per LDS chunk
#define NCHB    32                   // chunks per book
#define PT      2                    // point tiles (32 pts each) per wave -> 64 pts/wave
#define BPTS    256                  // 4 waves * 64 points
#define SLOTS   9                    // 8 f16 A-slots + 1 csq slot
#define CHUNK_BYTES (SLOTS * 1024)   // 9216 B
#define CHUNK_U16   (SLOTS * 512)    // 4608
#define EPS_ACC 0.05f                // >10 sigma of f16 dot error (sigma_diff ~4.5e-3)
#define WLB_CAP 32768                // per-book worklist cap

typedef _Float16 f16x8 __attribute__((ext_vector_type(8)));
typedef float    f32x16 __attribute__((ext_vector_type(16)));
typedef unsigned short u16;

// ws layout: cbf (4*32*9216 = 1179648 B) | csq fp32[4096] | counters int[4] | worklist int[4][32768]
#define WS_CSQ_OFF  2359296u
#define WS_CNT_OFF  (WS_CSQ_OFF + 16384u)
#define WS_WL_OFF   (WS_CNT_OFF + 256u)

__device__ inline u16 f16bits(_Float16 h) {
    union { _Float16 f; u16 u; } c; c.f = h; return c.u;
}

__device__ inline void async_copy16(const void* g, void* l) {
    __builtin_amdgcn_global_load_lds(
        (const __attribute__((address_space(1))) void*)g,
        (__attribute__((address_space(3))) void*)l,
        16, 0, 0);
}

// ---------------- prep: codebook -> f16 A-fragments (32x32x16) + csq slot + csq --------
// cbf per (b,chunk): slot s(0..7) at s*1024: A-frag f16 of dims [s*16, s*16+16)
//   frag: row(code-in-chunk) = lane&31, k = (lane>>5)*8 + j  (same k-map as B side)
// slot 8 at 8192: csq slice: lanes<32: k0=csq_hi,k1=csq_mid,k2=csq_rem (x -0.5), k3=320 (x 1.0)
__global__ __launch_bounds__(256)
void prep_kernel(const float* __restrict__ cb, char* __restrict__ cbf,
                 float* __restrict__ csq, int* __restrict__ counters) {
    if (blockIdx.x >= 256) {                       // csq + csq-slot + counter blocks (16)
        int idx = (blockIdx.x - 256) * 256 + threadIdx.x;   // 0..4095
        if (idx < 4) counters[idx] = 0;
        const float4* p = (const float4*)(cb + (size_t)idx * DIM);
        float s = 0.f;
#pragma unroll
        for (int i = 0; i < DIM / 4; ++i) {
            float4 v = p[i];
            s += v.x * v.x + v.y * v.y + v.z * v.z + v.w * v.w;
        }
        csq[idx] = s;
        int b = idx >> 10, k = idx & 1023;
        _Float16 hi  = (_Float16)s;
        float    r1  = s - (float)hi;
        _Float16 mid = (_Float16)r1;
        _Float16 rem = (_Float16)(r1 - (float)mid);
        u16* dst = (u16*)(cbf + (size_t)(b * 32 + (k >> 5)) * CHUNK_BYTES
                              + 8192 + (size_t)(k & 31) * 16);
        u16 o[8] = {f16bits(hi), f16bits(mid), f16bits(rem), (u16)0x5D00, 0, 0, 0, 0};
#pragma unroll
        for (int j = 0; j < 8; ++j) dst[j] = o[j];
        u16* dz = dst + 32 * 8;                    // lanes 32..63 of slot 8 = 0
#pragma unroll
        for (int j = 0; j < 8; ++j) dz[j] = 0;
        return;
    }
    int t    = blockIdx.x * 256 + threadIdx.x;     // 0..65535
    int lane = t & 63;
    int s    = (t >> 6) & 7;
    int bc   = t >> 9;                             // 0..127  (b*32 + chunk)
    int code = (bc & 31) * CHUNK + (lane & 31);
    int b    = bc >> 5;
    int dd   = s * 16 + (lane >> 5) * 8;

    const float* row = cb + ((size_t)b * KCODES + code) * DIM + dd;
    float4 v0 = ((const float4*)row)[0];
    float4 v1 = ((const float4*)row)[1];
    float vals[8] = {v0.x, v0.y, v0.z, v0.w, v1.x, v1.y, v1.z, v1.w};
    u16 o[8];
#pragma unroll
    for (int j = 0; j < 8; ++j) o[j] = f16bits((_Float16)vals[j]);
    u16* dst = (u16*)(cbf + (size_t)bc * CHUNK_BYTES + (size_t)s * 1024 + (size_t)lane * 16);
#pragma unroll
    for (int j = 0; j < 8; ++j) dst[j] = o[j];
}

// ---------------- main: R0 skeleton, f16 single plane (9 MFMA/pt/chunk vs 25) ----------
// grid (512, 2): block y handles books {2y, 2y+1} as one 64-chunk stream
__global__ __launch_bounds__(256, 3)
void argmin_mfma_kernel(const float* __restrict__ x,
                        const u16*  __restrict__ cbf,
                        int* __restrict__ out,
                        int* __restrict__ counters,
                        int* __restrict__ worklist) {
    __shared__ u16 lds[2 * CHUNK_U16];             // 18432 B (two 9.2 KB buffers)

    const int tid  = threadIdx.x;
    const int lane = tid & 63;
    const int w    = tid >> 6;
    const int n0   = blockIdx.x * BPTS;
    const int col  = lane & 31;
    const int kh   = lane >> 5;

    const char* src0 = (const char*)cbf + (size_t)(blockIdx.y * 64) * CHUNK_BYTES;

    auto issue = [&](int c) {                      // stage chunk c -> buf[c&1]
        const char* src = src0 + (size_t)c * CHUNK_BYTES;
        char* dst = (char*)&lds[(c & 1) * CHUNK_U16];
#pragma unroll
        for (int i = 0; i < 2; ++i)
            async_copy16(src + i * 4096 + tid * 16, dst + i * 4096 + w * 1024);
        if (w == 0)
            async_copy16(src + 8192 + lane * 16, dst + 8192);
    };

    issue(0);                                      // chunk 0 in flight during x-convert

    // ---- B fragments (points), f16, in regs (overlaps chunk-0 staging) ----
    f16x8 xh[PT][8];
#pragma unroll
    for (int pt = 0; pt < PT; ++pt) {
        const float* xrow = x + (size_t)(n0 + w * 64 + pt * 32 + col) * DIM;
#pragma unroll
        for (int s = 0; s < 8; ++s) {
            const float* p = xrow + s * 16 + kh * 8;
            float4 v0 = *(const float4*)p;
            float4 v1 = *(const float4*)(p + 4);
            float vals[8] = {v0.x, v0.y, v0.z, v0.w, v1.x, v1.y, v1.z, v1.w};
            f16x8 hv;
#pragma unroll
            for (int j = 0; j < 8; ++j) hv[j] = (_Float16)vals[j];
            xh[pt][s] = hv;
        }
    }
    f16x8 xcf;                                     // csq-slice B frag
#pragma unroll
    for (int j = 0; j < 8; ++j) {
        _Float16 v = (_Float16)0.0f;
        if (kh == 0) {
            if (j < 3) v = (_Float16)(-0.5f);
            else if (j == 3) v = (_Float16)1.0f;
        }
        xcf[j] = v;
    }

    unsigned b1p[PT], b2p[PT];
    int bchunk[PT];
#pragma unroll
    for (int pt = 0; pt < PT; ++pt) { b1p[pt] = 0u; b2p[pt] = 0u; bchunk[pt] = 0; }

    auto mfma_chunk = [&](const u16* A, f32x16* ac) {
#pragma unroll
        for (int pt = 0; pt < PT; ++pt)
#pragma unroll
            for (int r = 0; r < 16; ++r) ac[pt][r] = 0.f;
#pragma unroll
        for (int s = 0; s < 8; ++s) {
            f16x8 ah = *(const f16x8*)&A[s * 512 + lane * 8];
#pragma unroll
            for (int pt = 0; pt < PT; ++pt)
                ac[pt] = __builtin_amdgcn_mfma_f32_32x32x16_f16(ah, xh[pt][s], ac[pt], 0, 0, 0);
        }
        f16x8 acs = *(const f16x8*)&A[8 * 512 + lane * 8];
#pragma unroll
        for (int pt = 0; pt < PT; ++pt)                 // acc = dot - csq/2 + 320
            ac[pt] = __builtin_amdgcn_mfma_f32_32x32x16_f16(acs, xcf, ac[pt], 0, 0, 0);
    };

    auto epilogue = [&](const f32x16* ac, int cc) {     // packed top-2, larger = nearer
        int ci = cc & 31;
#pragma unroll
        for (int pt = 0; pt < PT; ++pt) {
            unsigned prev = b1p[pt], p1v = prev, p2v = b2p[pt];
#pragma unroll
            for (int r = 0; r < 16; r += 2) {
                unsigned pa = (__float_as_uint(ac[pt][r])     & 0xFFFFFFE0u) | (31u - (unsigned)r);
                unsigned pb = (__float_as_uint(ac[pt][r + 1]) & 0xFFFFFFE0u) | (30u - (unsigned)r);
                unsigned hi = pa > pb ? pa : pb;
                unsigned lo = pa < pb ? pa : pb;
                unsigned t2 = hi < p1v ? hi : p1v;
                unsigned m  = lo > t2 ? lo : t2;
                p2v = p2v > m ? p2v : m;                // -> v_max3
                p1v = p1v > hi ? p1v : hi;
            }
            bchunk[pt] = (p1v != prev) ? ci : bchunk[pt];
            b1p[pt] = p1v; b2p[pt] = p2v;
        }
    };

    auto finalize = [&](int book) {
        int b = blockIdx.y * 2 + book;
#pragma unroll
        for (int pt = 0; pt < PT; ++pt) {
            unsigned r = 31u - (b1p[pt] & 31u);         // leaf 0..15
            float m1 = __uint_as_float(b1p[pt] & 0xFFFFFFE0u);
            float m2 = __uint_as_float(b2p[pt] & 0xFFFFFFE0u);
            int row = (int)((r & 3u) + 8u * (r >> 2)) + 4 * kh;
            int code = bchunk[pt] * CHUNK + row;
            float om1 = __shfl_xor(m1, 32);
            float om2 = __shfl_xor(m2, 32);
            int   oc  = __shfl_xor(code, 32);
            bool take = (om1 > m1) || (om1 == m1 && oc < code);
            float nm2 = fmaxf(fminf(m1, om1), fmaxf(m2, om2));
            if (take) { m1 = om1; code = oc; }
            m2 = nm2;
            if (lane < 32) {
                int point = n0 + w * 64 + pt * 32 + col;
                out[point * NBOOK + b] = code;
                if (m1 - m2 < EPS_ACC) {
                    int pos = atomicAdd(&counters[b], 1);
                    if (pos < WLB_CAP) worklist[b * WLB_CAP + pos] = point;
                }
            }
            b1p[pt] = 0u; b2p[pt] = 0u; bchunk[pt] = 0;
        }
    };

    __syncthreads();                               // chunk 0 visible

    f32x16 acc0[PT], acc1[PT];
    for (int c = 0; c < 64; c += 2) {
        // ---- even chunk: buf0/acc0; epilogue of odd chunk c-1 deferred here ----
        issue(c + 1);
        mfma_chunk(lds, acc0);
        if (c > 0) {
            epilogue(acc1, c - 1);
            if (c == 32) finalize(0);              // after chunk31 epilogue
        }
        __syncthreads();                           // loads c+1 done; buf0 reads done

        // ---- odd chunk: buf1/acc1; epilogue of even chunk c deferred here ----
        if (c + 2 < 64) issue(c + 2);
        mfma_chunk(lds + CHUNK_U16, acc1);
        epilogue(acc0, c);
        __syncthreads();                           // loads c+2 done; buf1 reads done
    }
    epilogue(acc1, 63);
    finalize(1);
}

// ---------------- fallback: exact fp32, ONE ITEM PER WAVE, coalesced + shfl-reduce -----
// grid (512, 4): y = book. Per wave-iteration: 4 codes; 16-lane group g owns code 4it+g,
// lane owns 8 dims -> loads are 64 lanes x 32B contiguous (2KB, perfectly coalesced,
// L2-resident). Reduce via shfl_xor tree. ~4 us per item-wave, fully parallel.
__global__ __launch_bounds__(256)
void exact_kernel(const float* __restrict__ x,
                  const float* __restrict__ cb,
                  const float* __restrict__ csq,
                  const int* __restrict__ counters,
                  const int* __restrict__ worklist,
                  int* __restrict__ out) {
    const int b = blockIdx.y;
    int n = counters[b];
    if (n > WLB_CAP) n = WLB_CAP;
    const int lane = threadIdx.x & 63;
    const int w    = threadIdx.x >> 6;
    const int g    = lane >> 4;                    // code sub-group 0..3
    const int d0   = (lane & 15) * 8;              // my 8 dims
    const float* cbb = cb + (size_t)b * KCODES * DIM;
    const float* csb = csq + b * KCODES;

    for (int i = blockIdx.x * 4 + w; i < n; i += gridDim.x * 4) {
        int point = worklist[b * WLB_CAP + i];
        const float* xr = x + (size_t)point * DIM + d0;
        float4 xa = ((const float4*)xr)[0];
        float4 xb = ((const float4*)xr)[1];
        float bd = 3.4e38f;
        int   bi = 0;
#pragma unroll 4
        for (int it = 0; it < 256; ++it) {
            int c0 = it * 4 + g;
            const float* cr = cbb + (size_t)c0 * DIM + d0;
            float4 ca = ((const float4*)cr)[0];
            float4 cc = ((const float4*)cr)[1];
            float p = xa.x * ca.x + xa.y * ca.y + xa.z * ca.z + xa.w * ca.w
                    + xb.x * cc.x + xb.y * cc.y + xb.z * cc.z + xb.w * cc.w;
            p += __shfl_xor(p, 1);
            p += __shfl_xor(p, 2);
            p += __shfl_xor(p, 4);
            p += __shfl_xor(p, 8);
            float dist = csb[c0] - 2.f * p;
            if (dist < bd) { bd = dist; bi = c0; }  // strict < keeps lowest index
        }
#pragma unroll
        for (int off = 16; off <= 32; off <<= 1) {
            float od = __shfl_xor(bd, off);
            int   oi = __shfl_xor(bi, off);
            if (od < bd || (od == bd && oi < bi)) { bd = od; bi = oi; }
        }
        if (lane == 0) out[point * NBOOK + b] = bi;
    }
}

extern "C" void kernel_launch(void* const* d_in, const int* in_sizes, int n_in,
                              void* d_out, int out_size, void* d_ws, size_t ws_size,
                              hipStream_t stream) {
    const float* x  = (const float*)d_in[0];   // [N, D] fp32
    const float* cb = (const float*)d_in[1];   // [B, K, D] fp32
    int* out = (int*)d_out;                    // [N, B] int32

    char* ws = (char*)d_ws;
    u16*   cbf      = (u16*)ws;
    float* csq      = (float*)(ws + WS_CSQ_OFF);
    int*   counters = (int*)(ws + WS_CNT_OFF);
    int*   worklist = (int*)(ws + WS_WL_OFF);

    prep_kernel<<<272, 256, 0, stream>>>(cb, (char*)cbf, csq, counters);

    argmin_mfma_kernel<<<dim3(N_PTS / BPTS, 2), 256, 0, stream>>>(x, cbf, out, counters, worklist);

    exact_kernel<<<dim3(512, 4), 256, 0, stream>>>(x, cb, csq, counters, worklist, out);
}